// Round 11
// baseline (351.513 us; speedup 1.0000x reference)
//
#include <hip/hip_runtime.h>

#define HH 20
#define WW 20
#define TT 96
#define BB 64
#define SIG 306
#define NFC 17
#define TSTRIDE 264    // feat per-t stride: 16pix*16ch + 8 (bank de-alias)
#define CHUNK 16
#define NCHUNK 6
#define XT 199         // xs per-t stride
#define SIGP 308       // sigLDS per-pixel stride (306 + 2 pad)

typedef float float4u __attribute__((ext_vector_type(4), aligned(4)));

// ---------------------------------------------------------------------------
// Kernel 1: conv + signature + fused MLP-1. sig NEVER touches HBM.
// Block = 256 thr = one (b, 4x4-pixel tile). Grid = 25 tiles * 64 b = 1600,
// TILE-MAJOR so the 64 co-resident same-tile blocks share one 627 KB w1
// tile in L2/L3. Main body identical to the frozen 144-us r7 kernel.
// Epilogue: sig regs -> LDS [pix][k] tile (overlays dead feat/xs), then
// thread = (pix, n-quad, k-half) streams w1 as dense k-sequential float4
// loads (4-reg accumulator, no r9-style VGPR blowup), LDS reduce, 32
// atomicAdds per block onto acc[64][32].
// ---------------------------------------------------------------------------
__global__ __launch_bounds__(256) void sig_fused(
    const float* __restrict__ x,    // (64,96,4,20,20)
    const float* __restrict__ cw,   // (12,4,3,3)
    const float* __restrict__ w1,   // (122400,32)
    float* __restrict__ acc)        // (64,32) zeroed
{
  __shared__ __align__(16) float smem[7984];   // 31.9 KB total
  float* feat = smem;                // 4224 = 15*264 + 256 + 8
  float* xs   = smem + 4224;         // 3184 = 16*199
  float* wlds = smem + 7408;         // 576
  // epilogue overlay (feat/xs dead by then):
  float* sigL = smem;                // 4928 = 16*308
  float* redL = smem + 4928;         // 1024 = 32n * 32

  const int tid = threadIdx.x;
  const int blk = blockIdx.x;
  const int tile = blk >> 6;          // 0..24  (tile-major!)
  const int b    = blk & 63;
  const int th4 = (tile / 5) * 4, tw4 = (tile % 5) * 4;
  const float* xb0 = x + (size_t)b * TT * 1600;

  // ---- stage conv weights (bias dropped: signature bias-invariant) ----
  #pragma unroll
  for (int r = 0; r < 3; r++) {
    int idx = r * 256 + tid;
    if (idx < 576) {
      int k = idx / 48, rem = idx % 48;
      int ci = rem / 12, r2 = rem % 12, dy = r2 >> 2, dx = r2 & 3;
      wlds[idx] = (dx < 3) ? cw[k * 36 + ci * 9 + dy * 3 + dx] : 0.f;
    }
  }

  // ---- staging precompute: 2304 = 9*256 halo values per chunk ----
  int g_off[9], l_off[9];
  #pragma unroll
  for (int r = 0; r < 9; r++) {
    int idx = r * 256 + tid;
    int t = idx / 144, q = idx % 144;
    int ci = q / 36, pos = q % 36, row = pos / 6, col = pos % 6;
    int gr = th4 - 1 + row, gc = tw4 - 1 + col;
    bool valid = (gr >= 0 && gr < HH && gc >= 0 && gc < WW);
    g_off[r] = valid ? (t * 1600 + ci * 400 + gr * WW + gc) : -1;
    l_off[r] = t * XT + ci * 48 + row * 8 + col;
  }

  const int cpix = tid >> 4, ctt = tid & 15;
  const int cpy = cpix >> 2, cpx = cpix & 3;

  const int p2 = tid >> 4;
  const int rr = tid & 15, it = rr >> 2, jt = rr & 3;
  const int i0 = it * 4, j0 = jt * 4;

  float accv[4][4];
  float f0a[4], f0b[4], pa[4], pb[4], fsum[4];
  #pragma unroll
  for (int i = 0; i < 4; i++) {
    #pragma unroll
    for (int j = 0; j < 4; j++) accv[i][j] = 0.f;
  }

  auto stage = [&](int chunk) {
    const float* xbc = xb0 + (size_t)chunk * CHUNK * 1600;
    float rg[9];
    #pragma unroll
    for (int r = 0; r < 9; r++)
      rg[r] = (g_off[r] >= 0) ? xbc[g_off[r]] : 0.f;
    #pragma unroll
    for (int r = 0; r < 9; r++) xs[l_off[r]] = rg[r];
  };

  auto conv = [&]() {
    float win[4][9];
    const int wb2 = ctt * XT;
    #pragma unroll
    for (int ci = 0; ci < 4; ci++)
      #pragma unroll
      for (int dy = 0; dy < 3; dy++)
        #pragma unroll
        for (int dxx = 0; dxx < 3; dxx++)
          win[ci][dy * 3 + dxx] = xs[wb2 + ci * 48 + (cpy + dy) * 8 + (cpx + dxx)];

    float fk[12];
    #pragma unroll
    for (int k = 0; k < 12; k++) {
      float a = 0.f;
      #pragma unroll
      for (int ci = 0; ci < 4; ci++) {
        #pragma unroll
        for (int dy = 0; dy < 3; dy++) {
          const float4 w4 = *reinterpret_cast<const float4*>(
              &wlds[k * 48 + ci * 12 + dy * 4]);
          a += win[ci][dy * 3 + 0] * w4.x + win[ci][dy * 3 + 1] * w4.y +
               win[ci][dy * 3 + 2] * w4.z;
        }
      }
      fk[k] = a;
    }
    float* fr = &feat[ctt * TSTRIDE + cpix * 16];
    *reinterpret_cast<float4*>(fr + 0)  = make_float4(fk[0], fk[1], fk[2], fk[3]);
    *reinterpret_cast<float4*>(fr + 4)  = make_float4(fk[4], fk[5], fk[6], fk[7]);
    *reinterpret_cast<float4*>(fr + 8)  = make_float4(fk[8], fk[9], fk[10], fk[11]);
    *reinterpret_cast<float4*>(fr + 12) = make_float4(win[0][4], win[1][4], win[2][4], win[3][4]);
  };

  auto p2step = [&](int tt) {
    const float* row = &feat[tt * TSTRIDE + p2 * 16];
    const float4 a4 = *reinterpret_cast<const float4*>(row + i0);
    const float4 b4 = *reinterpret_cast<const float4*>(row + j0);
    float fa[4] = {a4.x, a4.y, a4.z, a4.w};
    float fb[4] = {b4.x, b4.y, b4.z, b4.w};
    float sa[4], db[4];
    #pragma unroll
    for (int i = 0; i < 4; i++) { sa[i] = fa[i] + pa[i]; db[i] = fb[i] - pb[i]; }
    #pragma unroll
    for (int i = 0; i < 4; i++)
      #pragma unroll
      for (int j = 0; j < 4; j++) accv[i][j] += sa[i] * db[j];
    #pragma unroll
    for (int i = 0; i < 4; i++) { fsum[i] += fa[i]; pa[i] = fa[i]; pb[i] = fb[i]; }
  };

  // ===== chunk 0 (peeled) =====
  stage(0);
  __syncthreads();
  conv();
  __syncthreads();
  {
    const float* r0 = &feat[p2 * 16];
    const float4 a4 = *reinterpret_cast<const float4*>(r0 + i0);
    const float4 b4 = *reinterpret_cast<const float4*>(r0 + j0);
    f0a[0] = a4.x; f0a[1] = a4.y; f0a[2] = a4.z; f0a[3] = a4.w;
    f0b[0] = b4.x; f0b[1] = b4.y; f0b[2] = b4.z; f0b[3] = b4.w;
    #pragma unroll
    for (int i = 0; i < 4; i++) { pa[i] = f0a[i]; pb[i] = f0b[i]; fsum[i] = f0a[i]; }
  }
  #pragma unroll
  for (int tt = 1; tt < CHUNK; tt++) p2step(tt);

  // ===== chunks 1..5 =====
  for (int chunk = 1; chunk < NCHUNK; chunk++) {
    __syncthreads();
    stage(chunk);
    __syncthreads();
    conv();
    __syncthreads();
    #pragma unroll
    for (int tt = 0; tt < CHUNK; tt++) p2step(tt);
  }

  // ===== sig regs -> LDS tile [pix][k] (overlays feat/xs) =====
  __syncthreads();   // all p2step feat reads done before overlay
  {
    float* sp = sigL + p2 * SIGP;
    float lv1b[4];
    #pragma unroll
    for (int j = 0; j < 4; j++) lv1b[j] = pb[j] - f0b[j];
    #pragma unroll
    for (int ii = 0; ii < 4; ii++)
      #pragma unroll
      for (int jj = 0; jj < 4; jj++)
        sp[NFC + (i0 + ii) * NFC + (j0 + jj)] =
            0.5f * accv[ii][jj] - f0a[ii] * lv1b[jj];
    if (jt == 0) {
      #pragma unroll
      for (int ii = 0; ii < 4; ii++) {
        const int c = i0 + ii;
        const float f0 = f0a[ii], f95 = pa[ii], fs = fsum[ii];
        sp[c] = f95 - f0;                                            // lvl1
        sp[NFC + c * NFC + 16] = (fs - 95.5f * f0 - 0.5f * f95) * (1.f / 95.f);
        sp[NFC + 16 * NFC + c] = (95.5f * f95 + 0.5f * f0 - fs) * (1.f / 95.f);
      }
      if (it == 0) { sp[16] = 1.0f; sp[NFC + 16 * NFC + 16] = 0.5f; }
    }
  }
  __syncthreads();

  // ===== fused MLP-1 epilogue: thread = (pix, n-quad, k-half) =====
  {
    const int epix = tid >> 4, sub = tid & 15;
    const int nq = sub >> 1, kh = sub & 1;
    const int pg = (th4 + (epix >> 2)) * WW + (tw4 + (epix & 3));
    const float* wb = w1 + ((size_t)pg * SIG + kh * 152) * 32 + nq * 4;
    const float* sp = sigL + epix * SIGP + kh * 152;

    float a0 = 0.f, a1 = 0.f, a2 = 0.f, a3 = 0.f;
    #pragma unroll 2
    for (int kq = 0; kq < 38; kq++) {
      const float4 s4 = *reinterpret_cast<const float4*>(sp + kq * 4);
      const float4 w0 = *reinterpret_cast<const float4*>(wb + (size_t)(kq * 4 + 0) * 32);
      const float4 w1v = *reinterpret_cast<const float4*>(wb + (size_t)(kq * 4 + 1) * 32);
      const float4 w2v = *reinterpret_cast<const float4*>(wb + (size_t)(kq * 4 + 2) * 32);
      const float4 w3v = *reinterpret_cast<const float4*>(wb + (size_t)(kq * 4 + 3) * 32);
      a0 += s4.x * w0.x + s4.y * w1v.x + s4.z * w2v.x + s4.w * w3v.x;
      a1 += s4.x * w0.y + s4.y * w1v.y + s4.z * w2v.y + s4.w * w3v.y;
      a2 += s4.x * w0.z + s4.y * w1v.z + s4.z * w2v.z + s4.w * w3v.z;
      a3 += s4.x * w0.w + s4.y * w1v.w + s4.z * w2v.w + s4.w * w3v.w;
    }
    if (kh) {   // k = 304, 305
      const float sA = sp[152], sB = sp[153];
      const float4 wA = *reinterpret_cast<const float4*>(wb + (size_t)152 * 32);
      const float4 wB = *reinterpret_cast<const float4*>(wb + (size_t)153 * 32);
      a0 += sA * wA.x + sB * wB.x;
      a1 += sA * wA.y + sB * wB.y;
      a2 += sA * wA.z + sB * wB.z;
      a3 += sA * wA.w + sB * wB.w;
    }

    // redL[n][pix*2+kh], n = nq*4+c
    redL[(nq * 4 + 0) * 32 + epix * 2 + kh] = a0;
    redL[(nq * 4 + 1) * 32 + epix * 2 + kh] = a1;
    redL[(nq * 4 + 2) * 32 + epix * 2 + kh] = a2;
    redL[(nq * 4 + 3) * 32 + epix * 2 + kh] = a3;
  }
  __syncthreads();

  if (tid < 32) {
    const float* rp = redL + tid * 32;
    float s = 0.f;
    #pragma unroll
    for (int q = 0; q < 8; q++) {
      const float4 v = *reinterpret_cast<const float4*>(rp + q * 4);
      s += (v.x + v.y) + (v.z + v.w);
    }
    atomicAdd(&acc[b * 32 + tid], s);
  }
}

// ---------------------------------------------------------------------------
// Kernel 2: MLP layers 2-4. 64 blocks (one per b); lanes 0..31 of one wave.
// ---------------------------------------------------------------------------
__global__ __launch_bounds__(64) void mlp_tail(
    const float* __restrict__ acc, const float* __restrict__ b1,
    const float* __restrict__ w2, const float* __restrict__ b2,
    const float* __restrict__ w3, const float* __restrict__ b3,
    const float* __restrict__ w4, const float* __restrict__ b4,
    float* __restrict__ out)
{
  const int n = threadIdx.x & 31;
  const int b = blockIdx.x;
  if (threadIdx.x >= 32) return;

  float h = fmaxf(acc[b * 32 + n] + b1[n], 0.f);

  float v = b2[n];
  #pragma unroll
  for (int k = 0; k < 32; k++)
    v += __shfl(h, k, 64) * w2[k * 32 + n];
  h = fmaxf(v, 0.f);

  v = b3[n];
  #pragma unroll
  for (int k = 0; k < 32; k++)
    v += __shfl(h, k, 64) * w3[k * 32 + n];
  h = fmaxf(v, 0.f);

  float p = h * w4[n];
  #pragma unroll
  for (int o = 16; o >= 1; o >>= 1) p += __shfl_xor(p, o, 64);
  if (n == 0) out[b] = p + b4[0];
}

extern "C" void kernel_launch(void* const* d_in, const int* in_sizes, int n_in,
                              void* d_out, int out_size, void* d_ws, size_t ws_size,
                              hipStream_t stream) {
  const float* x  = (const float*)d_in[0];
  const float* cw = (const float*)d_in[1];
  const float* w1 = (const float*)d_in[3];
  const float* b1 = (const float*)d_in[4];
  const float* w2 = (const float*)d_in[5];
  const float* b2 = (const float*)d_in[6];
  const float* w3 = (const float*)d_in[7];
  const float* b3 = (const float*)d_in[8];
  const float* w4 = (const float*)d_in[9];
  const float* b4 = (const float*)d_in[10];
  float* out = (float*)d_out;
  float* acc = (float*)d_ws;   // 64*32 fp32 = 8 KB

  hipMemsetAsync(acc, 0, BB * 32 * sizeof(float), stream);
  sig_fused<<<dim3(1600), dim3(256), 0, stream>>>(x, cw, w1, acc);
  mlp_tail<<<dim3(64), dim3(64), 0, stream>>>(acc, b1, w2, b2, w3, b3, w4, b4, out);
}